// Round 6
// baseline (437.324 us; speedup 1.0000x reference)
//
#include <hip/hip_runtime.h>

// out[n] = image[3*(n/3) + perm[n]], N = 4096*4096*3 floats.
// R9: R8 (LDS neighbor exchange, verified 137.5 us) + ONE change:
// non-temporal stores for the output.
// Theory: inputs (402 MB) vs L3 (256 MB); FETCH_SIZE shows only ~48% of
// reads hit L3. The output (201 MB, write-once, never re-read) allocates in
// cache and evicts input lines — and between bench iterations leaves L3
// holding output instead of the inputs the next dispatch reads. Occupancy
// and ILP are maxed (R7: 2x ILP = no delta), so the per-CU outstanding-miss
// capacity is the binding concurrency; the only remaining lever is lower
// average load latency via higher L3 read-hit rate. NT stores free the
// full L3 for inputs (hit rate -> ~64%).
// Everything else byte-identical to R8: requests at the 604 MB floor.

typedef float f32x4 __attribute__((ext_vector_type(4)));
typedef int   i32x4 __attribute__((ext_vector_type(4)));

#define BLOCK 256

__device__ __forceinline__ float sel8(float c0, float c1, float c2, float c3,
                                      float c4, float c5, float c6, float c7,
                                      int idx) {
    // 8-way select, 7 v_cndmask tree (idx in [0,7])
    float s01 = (idx & 1) ? c1 : c0;
    float s23 = (idx & 1) ? c3 : c2;
    float s45 = (idx & 1) ? c5 : c4;
    float s67 = (idx & 1) ? c7 : c6;
    float s03 = (idx & 2) ? s23 : s01;
    float s47 = (idx & 2) ? s67 : s45;
    return (idx & 4) ? s47 : s03;
}

__global__ __launch_bounds__(BLOCK) void PerPixelChannelPermutation_kernel(
    const float* __restrict__ img, const i32x4* __restrict__ perm4,
    f32x4* __restrict__ out4, int nchunks, int n_elems) {
    __shared__ f32x4 sv[BLOCK];

    const int tid = threadIdx.x;
    const int c   = blockIdx.x * BLOCK + tid;  // exact grid, no tail
    const int c4  = c * 4;

    const f32x4* img4 = (const f32x4*)img;

    // Main loads: img first (ds_write waits only on it, perm stays in
    // flight through the barrier), both lane-contiguous 16B.
    const f32x4 v  = img4[c];   // img[4c .. 4c+3]
    const i32x4 qq = perm4[c];  // perm[4c .. 4c+3]

    // Edge patch loads issued early (2 threads per block), in flight
    // across the barrier.
    float e0 = 0.f, e1 = 0.f;
    if (tid == 0) {
        int b = c4 - 2; if (b < 0) b = 0;  // c==0: idx 0,1 unreachable, clamp safe
        e0 = img[b];
        e1 = img[b + 1];
    }
    if (tid == BLOCK - 1) {
        int b = c4 + 4; if (b > n_elems - 2) b = n_elems - 2;  // last chunk: idx 6,7 unreachable
        e0 = img[b];
        e1 = img[b + 1];
    }

    sv[tid] = v;            // ds_write_b128, contiguous: conflict-free
    __syncthreads();

    // Neighbor quads via contiguous ds_read_b128 (2 lanes/bank = free).
    const int il = (tid == 0)         ? 0         : tid - 1;
    const int ih = (tid == BLOCK - 1) ? BLOCK - 1 : tid + 1;
    const f32x4 L = sv[il];
    const f32x4 H = sv[ih];

    float pm2 = L.z, pm1 = L.w;   // img[4c-2], img[4c-1]
    float nx0 = H.x, nx1 = H.y;   // img[4c+4], img[4c+5]
    if (tid == 0)         { pm2 = e0; pm1 = e1; }
    if (tid == BLOCK - 1) { nx0 = e0; nx1 = e1; }

    // p = (4c) % 3 = c % 3; candidate idx_k = off_k + perm_k over
    // [pm2, pm1, v.x, v.y, v.z, v.w, nx0, nx1] = img[4c-2 .. 4c+5]
    //   p=0: offs {2,2,2,5}   p=1: {1,1,4,4}   p=2: {0,3,3,3}
    const int p = c % 3;
    const int off0 = 2 - p;
    const int off3 = 5 - p;
    const int off1 = (p == 0) ? 2 : ((p == 1) ? 1 : 3);
    const int off2 = (p == 0) ? 2 : ((p == 1) ? 4 : 3);

    f32x4 o;
    o.x = sel8(pm2, pm1, v.x, v.y, v.z, v.w, nx0, nx1, off0 + qq.x);
    o.y = sel8(pm2, pm1, v.x, v.y, v.z, v.w, nx0, nx1, off1 + qq.y);
    o.z = sel8(pm2, pm1, v.x, v.y, v.z, v.w, nx0, nx1, off2 + qq.z);
    o.w = sel8(pm2, pm1, v.x, v.y, v.z, v.w, nx0, nx1, off3 + qq.w);

    __builtin_nontemporal_store(o, &out4[c]);  // coalesced; keep out of L3
}

extern "C" void kernel_launch(void* const* d_in, const int* in_sizes, int n_in,
                              void* d_out, int out_size, void* d_ws, size_t ws_size,
                              hipStream_t stream) {
    const float* img   = (const float*)d_in[0];
    const i32x4* perm4 = (const i32x4*)d_in[1];
    f32x4*       out4  = (f32x4*)d_out;

    const int n_elems = in_sizes[0];   // 4096*4096*3 = 50,331,648
    const int nchunks = n_elems / 4;   // 12,582,912 = 49152 * 256 (exact)

    const int grid = nchunks / BLOCK;  // 49152, exact — no tail
    PerPixelChannelPermutation_kernel<<<grid, BLOCK, 0, stream>>>(
        img, perm4, out4, nchunks, n_elems);
}